// Round 5
// baseline (240.697 us; speedup 1.0000x reference)
//
#include <hip/hip_runtime.h>
#include <hip/hip_bf16.h>

typedef __attribute__((ext_vector_type(4))) float f32x4;
typedef __attribute__((ext_vector_type(16))) float f32x16;
typedef __attribute__((ext_vector_type(8))) short short8;
typedef unsigned short ushort_t;

#define BATCH 256
#define PDIM 512
#define MDIM 768
#define XCOLS 1280
#define PROJ 512
#define HID 256
#define KTOT (PDIM * MDIM)

#define BN 32
#define NT 16       // N tiles (512/32)
#define PSPLIT 64   // pi splits
#define PI_PER 8    // 512/64
#define NJW 12      // j windows of 64
#define NSTEPS 96   // schedule: pil = (pil0+s)&7 inner, jw = (jw0 + s/8) % 12

__device__ __forceinline__ ushort_t f2bf(float f) {
  __hip_bfloat16 h = __float2bfloat16(f);
  return __builtin_bit_cast(ushort_t, h);
}
__device__ __forceinline__ float bf2f(ushort_t u) {
  union { unsigned int i; float f; } c;
  c.i = ((unsigned int)u) << 16;
  return c.f;
}

// ---------------- prep: p transpose + fragment-ordered bf16(m) ----------------
// mF chunk c = ((jw*8 + mf)*4 + ks)*64 + lane ; element e of chunk:
//   bf16( m[row = mf*32+(lane&31)][k = jw*64 + ks*16 + (lane>>5)*8 + e] )
__global__ void prep_kernel(const float* __restrict__ x, float* __restrict__ pT,
                            ushort_t* __restrict__ mF) {
  int tid = blockIdx.x * blockDim.x + threadIdx.x;
  int nth = gridDim.x * blockDim.x;
  for (int i = tid; i < PDIM * BATCH; i += nth) {
    int pi = i >> 8, b = i & 255;   // pT[pi][b]
    pT[i] = x[b * XCOLS + pi];
  }
  for (int c = tid; c < NJW * 8 * 4 * 64; c += nth) {
    int lane = c & 63;
    int ks = (c >> 6) & 3;
    int mf = (c >> 8) & 7;
    int jw = c >> 11;
    int row = mf * 32 + (lane & 31);
    int k0 = jw * 64 + ks * 16 + ((lane >> 5) << 3);
    const float* src = x + row * XCOLS + PDIM + k0;
    f32x4 v0 = *(const f32x4*)src;
    f32x4 v1 = *(const f32x4*)(src + 4);
    short8 o;
#pragma unroll
    for (int i = 0; i < 4; ++i) {
      o[i] = (short)f2bf(v0[i]);
      o[i + 4] = (short)f2bf(v1[i]);
    }
    ((short8*)mF)[c] = o;
  }
}

// ---------------- main einsum GEMM ----------------
// r4 structure (A in regs from fragment-ordered mF, B via 4KB dbuf LDS, one raw
// barrier + lgkmcnt(0) per step), PLUS: per-WG desynchronized (pil0,jw0) walk
// through the 96-step schedule, depth-2 W1 prefetch, non-temporal W1 loads.
__global__ __launch_bounds__(256, 3)
void einsum_kernel(const float* __restrict__ W1, const ushort_t* __restrict__ mF,
                   const float* __restrict__ pT, float* __restrict__ outp,
                   int atomic_mode) {
  __shared__ ushort_t Bf[2][2048];      // 2 x 4 KB B frags
  __shared__ float pl[PI_PER * BATCH];  // 8 KB p[pil][b]

  const int ntile = blockIdx.x & 15;
  const int ps    = blockIdx.x >> 4;
  const int pi0   = ps * PI_PER;
  const int n0    = ntile * BN;
  const int t     = threadIdx.x;
  const int lane  = t & 63;
  const int w     = t >> 6;   // 4 waves; wave w owns rows 64w..64w+63

  // per-WG schedule phase (desynchronize channel targeting chip-wide)
  const unsigned hsh = blockIdx.x * 2654435761u;
  const int pil0 = (hsh >> 8) & 7;
  const int jw0  = (int)((((hsh >> 16) & 0xffff) * 12u) >> 16);  // [0,12)

  // stage p for this WG's pi range (8 KB)
  {
    const f32x4* src = (const f32x4*)(pT + pi0 * BATCH);
    ((f32x4*)pl)[t] = src[t];
    ((f32x4*)pl)[t + 256] = src[t + 256];
  }

  // W1 staging map: thread = (row sn = t>>3 in 0..31, octet q = t&7)
  const int sn = t >> 3, q = t & 7;
  const float* wbase = W1 + (size_t)(n0 + sn) * KTOT + (size_t)pi0 * MDIM + q * 8;
  const int bwo = (((q >> 1) * 64) + ((q & 1) << 5) + sn) * 8;

  // k-offset (floats) of step tt in this WG's schedule
  auto koff = [&](int tt) {
    int pil = (pil0 + (tt & 7)) & 7;
    int g = jw0 + (tt >> 3);
    if (g >= NJW) g -= NJW;
    return pil * MDIM + g * 64;
  };

  // A fragment chunks in regs for current jw group
  const short8* mv = (const short8*)mF;
  const int mbase = w * 512 + lane;
  const short8* srcA = mv + jw0 * 2048;
  short8 ac0 = srcA[mbase];
  short8 ac1 = srcA[mbase + 64];
  short8 ac2 = srcA[mbase + 128];
  short8 ac3 = srcA[mbase + 192];
  short8 ac4 = srcA[mbase + 256];
  short8 ac5 = srcA[mbase + 320];
  short8 ac6 = srcA[mbase + 384];
  short8 ac7 = srcA[mbase + 448];

  // prologue: W1(0), W1(1) in flight (depth 2), non-temporal
  f32x4 wv0, wv1, nv0, nv1;
  {
    const float* p0 = wbase + koff(0);
    wv0 = __builtin_nontemporal_load((const f32x4*)p0);
    wv1 = __builtin_nontemporal_load((const f32x4*)(p0 + 4));
    const float* p1 = wbase + koff(1);
    nv0 = __builtin_nontemporal_load((const f32x4*)p1);
    nv1 = __builtin_nontemporal_load((const f32x4*)(p1 + 4));
  }

  f32x16 fa0, fa1;
#pragma unroll
  for (int i = 0; i < 16; ++i) { fa0[i] = 0.f; fa1[i] = 0.f; }

  __syncthreads();  // pl visibility

  for (int s = 0; s < NSTEPS; ++s) {
    // ---- issue W1(s+2): stays in flight across barriers (depth 2) ----
    int t2 = s + 2; t2 = (t2 >= NSTEPS) ? t2 - NSTEPS : t2;
    const float* wp2 = wbase + koff(t2);
    f32x4 xv0 = __builtin_nontemporal_load((const f32x4*)wp2);
    f32x4 xv1 = __builtin_nontemporal_load((const f32x4*)(wp2 + 4));

    // ---- cvt W1(s) -> bf16 frag, write to Bf[s&1] ----
    {
      short8 bs;
#pragma unroll
      for (int i = 0; i < 4; ++i) {
        bs[i]     = (short)f2bf(wv0[i]);
        bs[i + 4] = (short)f2bf(wv1[i]);
      }
      *(short8*)&Bf[s & 1][bwo] = bs;
    }
    asm volatile("s_waitcnt lgkmcnt(0)" ::: "memory");
    __builtin_amdgcn_s_barrier();
    asm volatile("" ::: "memory");

    // ---- read B frags + p scalars ----
    const short8* bf = (const short8*)Bf[s & 1];
    short8 bv0 = bf[lane];
    short8 bv1 = bf[lane + 64];
    short8 bv2 = bf[lane + 128];
    short8 bv3 = bf[lane + 192];
    const int pilc = (pil0 + (s & 7)) & 7;
    const float pa = pl[pilc * BATCH + w * 64 + (lane & 31)];
    const float pb = pl[pilc * BATCH + w * 64 + 32 + (lane & 31)];

    // ---- per-ks: scale A chunk by p, MFMA ----
#define GENMM(acA, acB, bv)                                          \
    {                                                                \
      short8 aA, aB;                                                 \
      _Pragma("unroll")                                              \
      for (int e = 0; e < 8; ++e) {                                  \
        aA[e] = (short)f2bf(pa * bf2f((ushort_t)acA[e]));            \
        aB[e] = (short)f2bf(pb * bf2f((ushort_t)acB[e]));            \
      }                                                              \
      fa0 = __builtin_amdgcn_mfma_f32_32x32x16_bf16(aA, bv, fa0, 0, 0, 0); \
      fa1 = __builtin_amdgcn_mfma_f32_32x32x16_bf16(aB, bv, fa1, 0, 0, 0); \
    }
    GENMM(ac0, ac4, bv0)
    GENMM(ac1, ac5, bv1)
    GENMM(ac2, ac6, bv2)
    GENMM(ac3, ac7, bv3)
#undef GENMM

    // ---- at group boundary: reload A chunks for next jw (L2-hot) ----
    if ((s & 7) == 7) {
      int g = jw0 + ((s + 1) >> 3);
      if (g >= NJW) g -= NJW;
      const short8* srcn = mv + g * 2048;
      ac0 = srcn[mbase];
      ac1 = srcn[mbase + 64];
      ac2 = srcn[mbase + 128];
      ac3 = srcn[mbase + 192];
      ac4 = srcn[mbase + 256];
      ac5 = srcn[mbase + 320];
      ac6 = srcn[mbase + 384];
      ac7 = srcn[mbase + 448];
    }

    wv0 = nv0; wv1 = nv1;
    nv0 = xv0; nv1 = xv1;
  }

  // ---- C write: row = 64w + (r&3)+8*(r>>2)+4*(lane>>5) (+32 for fa1), col = n0+(lane&31) ----
  const int col   = n0 + (lane & 31);
  const int rbase = w * 64 + ((lane >> 5) << 2);
  if (atomic_mode) {
#pragma unroll
    for (int r = 0; r < 16; ++r) {
      int row = rbase + (r & 3) + ((r >> 2) << 3);
      atomicAdd(&outp[(size_t)row * PROJ + col], fa0[r]);
      atomicAdd(&outp[(size_t)(row + 32) * PROJ + col], fa1[r]);
    }
  } else {
    float* dst = outp + (size_t)ps * BATCH * PROJ;
#pragma unroll
    for (int r = 0; r < 16; ++r) {
      int row = rbase + (r & 3) + ((r >> 2) << 3);
      dst[(size_t)row * PROJ + col] = fa0[r];
      dst[(size_t)(row + 32) * PROJ + col] = fa1[r];
    }
  }
}

// ---------------- reduce + LN + MLP ----------------
__global__ __launch_bounds__(256)
void mlp_kernel(const float* __restrict__ part, int nps,
                const float* __restrict__ b1, const float* __restrict__ lng,
                const float* __restrict__ lnb, const float* __restrict__ W2,
                const float* __restrict__ b2, const float* __restrict__ g1,
                const float* __restrict__ bb1, const float* __restrict__ W3,
                const float* __restrict__ b3, const float* __restrict__ g2,
                const float* __restrict__ bb2, const float* __restrict__ W4,
                const float* __restrict__ b4, float* __restrict__ out) {
  __shared__ float h1[PROJ];
  __shared__ float h2[HID];
  __shared__ float h3[HID / 2];
  __shared__ float red[16];
  const int b = blockIdx.x, t = threadIdx.x;

  float f0 = 0.f, f1 = 0.f;
  const float* p0 = part + (size_t)b * PROJ + t;
#pragma unroll 4
  for (int s = 0; s < nps; ++s) {
    f0 += p0[0];
    f1 += p0[256];
    p0 += (size_t)BATCH * PROJ;
  }
  f0 += b1[t];
  f1 += b1[t + 256];

  float sum = f0 + f1, ss = f0 * f0 + f1 * f1;
#pragma unroll
  for (int o = 32; o > 0; o >>= 1) {
    sum += __shfl_xor(sum, o);
    ss  += __shfl_xor(ss, o);
  }
  const int wv = t >> 6, ln = t & 63;
  if (ln == 0) { red[wv] = sum; red[8 + wv] = ss; }
  __syncthreads();
  sum = red[0] + red[1] + red[2] + red[3];
  ss  = red[8] + red[9] + red[10] + red[11];
  float mu   = sum * (1.f / 512.f);
  float var  = ss * (1.f / 512.f) - mu * mu;
  float rstd = rsqrtf(var + 1e-5f);
  h1[t]       = fmaxf(0.f, (f0 - mu) * rstd * lng[t] + lnb[t]);
  h1[t + 256] = fmaxf(0.f, (f1 - mu) * rstd * lng[t + 256] + lnb[t + 256]);
  __syncthreads();

  const float bninv = rsqrtf(1.f + 1e-5f);
  {
    const f32x4* wr = (const f32x4*)(W2 + (size_t)t * PROJ);
    const f32x4* hv = (const f32x4*)h1;
    float a = 0.f;
#pragma unroll 4
    for (int i = 0; i < PROJ / 4; ++i) {
      f32x4 wq = wr[i], h = hv[i];
      a += wq[0] * h[0] + wq[1] * h[1] + wq[2] * h[2] + wq[3] * h[3];
    }
    h2[t] = fmaxf(0.f, (a + b2[t]) * bninv * g1[t] + bb1[t]);
  }
  __syncthreads();
  if (t < 128) {
    const f32x4* wr = (const f32x4*)(W3 + (size_t)t * HID);
    const f32x4* hv = (const f32x4*)h2;
    float a = 0.f;
#pragma unroll 4
    for (int i = 0; i < HID / 4; ++i) {
      f32x4 wq = wr[i], h = hv[i];
      a += wq[0] * h[0] + wq[1] * h[1] + wq[2] * h[2] + wq[3] * h[3];
    }
    h3[t] = fmaxf(0.f, (a + b3[t]) * bninv * g2[t] + bb2[t]);
  }
  __syncthreads();
  if (t < 2) {
    const float* wr = W4 + t * 128;
    float a = 0.f;
#pragma unroll 4
    for (int i = 0; i < 128; ++i) a += wr[i] * h3[i];
    out[b * 2 + t] = a + b4[t];
  }
}

extern "C" void kernel_launch(void* const* d_in, const int* in_sizes, int n_in,
                              void* d_out, int out_size, void* d_ws, size_t ws_size,
                              hipStream_t stream) {
  const float* x   = (const float*)d_in[0];
  const float* W1  = (const float*)d_in[1];
  const float* b1  = (const float*)d_in[2];
  const float* lng = (const float*)d_in[3];
  const float* lnb = (const float*)d_in[4];
  const float* W2  = (const float*)d_in[5];
  const float* b2  = (const float*)d_in[6];
  const float* g1  = (const float*)d_in[7];
  const float* bb1 = (const float*)d_in[8];
  const float* W3  = (const float*)d_in[9];
  const float* b3  = (const float*)d_in[10];
  const float* g2  = (const float*)d_in[11];
  const float* bb2 = (const float*)d_in[12];
  const float* W4  = (const float*)d_in[13];
  const float* b4  = (const float*)d_in[14];
  float* out = (float*)d_out;

  char* ws = (char*)d_ws;
  float* pT    = (float*)ws;                 // 512 KB
  ushort_t* mF = (ushort_t*)(ws + 524288);   // 384 KB (fragment-ordered bf16 m)
  float* big   = (float*)(ws + 1048576);     // split-K partials

  size_t need = 1048576 + (size_t)PSPLIT * BATCH * PROJ * 4;
  bool partial = ws_size >= need;

  hipLaunchKernelGGL(prep_kernel, dim3(512), dim3(256), 0, stream, x, pT, mF);
  if (partial) {
    hipLaunchKernelGGL(einsum_kernel, dim3(NT * PSPLIT), dim3(256), 0, stream,
                       W1, mF, pT, big, 0);
    hipLaunchKernelGGL(mlp_kernel, dim3(BATCH), dim3(256), 0, stream, big, PSPLIT,
                       b1, lng, lnb, W2, b2, g1, bb1, W3, b3, g2, bb2, W4, b4, out);
  } else {
    hipMemsetAsync(big, 0, (size_t)BATCH * PROJ * 4, stream);
    hipLaunchKernelGGL(einsum_kernel, dim3(NT * PSPLIT), dim3(256), 0, stream,
                       W1, mF, pT, big, 1);
    hipLaunchKernelGGL(mlp_kernel, dim3(BATCH), dim3(256), 0, stream, big, 1,
                       b1, lng, lnb, W2, b2, g1, bb1, W3, b3, g2, bb2, W4, b4, out);
  }
}

// Round 6
// 226.104 us; speedup vs baseline: 1.0645x; 1.0645x over previous
//
#include <hip/hip_runtime.h>
#include <hip/hip_bf16.h>

typedef __attribute__((ext_vector_type(4))) float f32x4;
typedef __attribute__((ext_vector_type(16))) float f32x16;
typedef __attribute__((ext_vector_type(8))) short short8;
typedef __attribute__((ext_vector_type(4))) short short4v;
typedef unsigned short ushort_t;

#define BATCH 256
#define PDIM 512
#define MDIM 768
#define XCOLS 1280
#define PROJ 512
#define HID 256
#define KTOT (PDIM * MDIM)

#define BN 32
#define NT 16       // N tiles (512/32)
#define PSPLIT 64   // pi splits
#define PI_PER 8    // 512/64
#define NJW 12      // j windows of 64
#define NSTEPS 96   // s: pil = s&7 (inner), jw = s>>3

__device__ __forceinline__ ushort_t f2bf(float f) {
  __hip_bfloat16 h = __float2bfloat16(f);
  return __builtin_bit_cast(ushort_t, h);
}
__device__ __forceinline__ float bf2f(ushort_t u) {
  union { unsigned int i; float f; } c;
  c.i = ((unsigned int)u) << 16;
  return c.f;
}

// ---------------- prep: fragment-ordered bf16(m) only ----------------
// mF chunk c = ((jw*8 + mf)*4 + ks)*64 + lane ; element e of chunk:
//   bf16( m[row = mf*32+(lane&31)][k = jw*64 + ks*16 + (lane>>5)*8 + e] )
__global__ void prep_kernel(const float* __restrict__ x, ushort_t* __restrict__ mF) {
  int tid = blockIdx.x * blockDim.x + threadIdx.x;
  int nth = gridDim.x * blockDim.x;
  for (int c = tid; c < NJW * 8 * 4 * 64; c += nth) {
    int lane = c & 63;
    int ks = (c >> 6) & 3;
    int mf = (c >> 8) & 7;
    int jw = c >> 11;
    int row = mf * 32 + (lane & 31);
    int k0 = jw * 64 + ks * 16 + ((lane >> 5) << 3);
    const float* src = x + row * XCOLS + PDIM + k0;
    f32x4 v0 = *(const f32x4*)src;
    f32x4 v1 = *(const f32x4*)(src + 4);
    short8 o;
#pragma unroll
    for (int i = 0; i < 4; ++i) {
      o[i] = (short)f2bf(v0[i]);
      o[i + 4] = (short)f2bf(v1[i]);
    }
    ((short8*)mF)[c] = o;
  }
}

// ---------------- main einsum GEMM ----------------
// W1 staging with LINE-DENSE wave instructions: thread (r=t>>3, q=t&7) loads
// f32x4 at rowbase+16q B (instr covers full 128-B line of each of 8 rows, once)
// and rowbase+128+16q B. B-LDS: linear [32][64] bf16, XOR-swizzled
// (byte ^= (row&7)<<4); staged via 2 x ds_write_b64, frags read via ds_read_b128.
// A frags in regs from fragment-ordered mF (reload once per jw, L2-hot).
// One raw barrier + lgkmcnt(0) per step; W1 prefetch rides across the barrier.
__global__ __launch_bounds__(256, 4)
void einsum_kernel(const float* __restrict__ W1, const ushort_t* __restrict__ mF,
                   const float* __restrict__ x, float* __restrict__ outp,
                   int atomic_mode) {
  __shared__ ushort_t Bf[2][2048];      // 2 x 4 KB, swizzled linear [32][64]
  __shared__ float pl[PI_PER * BATCH];  // 8 KB p[pil][b]

  const int ntile = blockIdx.x & 15;
  const int ps    = blockIdx.x >> 4;
  const int pi0   = ps * PI_PER;
  const int n0    = ntile * BN;
  const int t     = threadIdx.x;
  const int lane  = t & 63;
  const int w     = t >> 6;   // 4 waves; wave w owns batch rows 64w..64w+63

  // stage p directly from x: thread t = batch row, 8 contiguous floats
  {
    const float* xr = x + (size_t)t * XCOLS + pi0;
    f32x4 v0 = *(const f32x4*)xr;
    f32x4 v1 = *(const f32x4*)(xr + 4);
    pl[t]             = v0[0];
    pl[256 + t]       = v0[1];
    pl[512 + t]       = v0[2];
    pl[768 + t]       = v0[3];
    pl[1024 + t]      = v1[0];
    pl[1280 + t]      = v1[1];
    pl[1536 + t]      = v1[2];
    pl[1792 + t]      = v1[3];
  }

  // W1 staging map: r = t>>3 (row 0..31), q = t&7 (16-B slot within line)
  const int r = t >> 3, q = t & 7;
  const float* wrow = W1 + (size_t)(n0 + r) * KTOT + (size_t)pi0 * MDIM;
  // swizzled LDS byte offsets for this thread's two 8-B frag writes
  const int wb0 = (r * 128 + q * 8) ^ ((r & 7) << 4);
  const int wb1 = (r * 128 + 64 + q * 8) ^ ((r & 7) << 4);

  // frag read base (byte): row=lane&31, hi=lane>>5; per-ks offset = bb0 ^ (ks<<5)
  const int bb0 = ((lane & 31) * 128 + ((lane >> 5) << 4)) ^ ((lane & 7) << 4);

  // A fragment chunks in regs: idx = jw*2048 + w*512 + mfl*256 + ks*64 + lane
  const short8* mv = (const short8*)mF;
  const int mbase = w * 512 + lane;
  short8 ac0 = mv[mbase];        // mf0 ks0
  short8 ac1 = mv[mbase + 64];
  short8 ac2 = mv[mbase + 128];
  short8 ac3 = mv[mbase + 192];
  short8 ac4 = mv[mbase + 256];  // mf1 ks0
  short8 ac5 = mv[mbase + 320];
  short8 ac6 = mv[mbase + 384];
  short8 ac7 = mv[mbase + 448];

  // prologue: W1(0) — line-dense: 16q B and 128+16q B
  f32x4 wv0 = __builtin_nontemporal_load((const f32x4*)(wrow + q * 4));
  f32x4 wv1 = __builtin_nontemporal_load((const f32x4*)(wrow + 32 + q * 4));

  f32x16 fa0, fa1;
#pragma unroll
  for (int i = 0; i < 16; ++i) { fa0[i] = 0.f; fa1[i] = 0.f; }

  for (int s = 0; s < NSTEPS; ++s) {
    // ---- issue W1(s+1): stays in flight across the barrier ----
    const int s1 = (s + 1 < NSTEPS) ? s + 1 : 0;
    const int kk1 = (s1 & 7) * MDIM + (s1 >> 3) * 64;
    f32x4 nv0 = __builtin_nontemporal_load((const f32x4*)(wrow + kk1 + q * 4));
    f32x4 nv1 = __builtin_nontemporal_load((const f32x4*)(wrow + kk1 + 32 + q * 4));

    // ---- cvt W1(s) -> bf16, 2 x b64 swizzled LDS writes ----
    {
      short4v lo, hi;
#pragma unroll
      for (int i = 0; i < 4; ++i) {
        lo[i] = (short)f2bf(wv0[i]);
        hi[i] = (short)f2bf(wv1[i]);
      }
      char* bbase = (char*)&Bf[s & 1][0];
      *(short4v*)(bbase + wb0) = lo;
      *(short4v*)(bbase + wb1) = hi;
    }
    asm volatile("s_waitcnt lgkmcnt(0)" ::: "memory");
    __builtin_amdgcn_s_barrier();
    asm volatile("" ::: "memory");

    // ---- read B frags (swizzled b128) + p scalars ----
    const char* rb = (const char*)&Bf[s & 1][0];
    short8 bv0 = *(const short8*)(rb + (bb0 ^ 0));
    short8 bv1 = *(const short8*)(rb + (bb0 ^ 32));
    short8 bv2 = *(const short8*)(rb + (bb0 ^ 64));
    short8 bv3 = *(const short8*)(rb + (bb0 ^ 96));
    const int pilc = s & 7;
    const float pa = pl[pilc * BATCH + w * 64 + (lane & 31)];
    const float pb = pl[pilc * BATCH + w * 64 + 32 + (lane & 31)];

    // ---- per-ks: scale A chunk by p, MFMA ----
#define GENMM(acA, acB, bv)                                          \
    {                                                                \
      short8 aA, aB;                                                 \
      _Pragma("unroll")                                              \
      for (int e = 0; e < 8; ++e) {                                  \
        aA[e] = (short)f2bf(pa * bf2f((ushort_t)acA[e]));            \
        aB[e] = (short)f2bf(pb * bf2f((ushort_t)acB[e]));            \
      }                                                              \
      fa0 = __builtin_amdgcn_mfma_f32_32x32x16_bf16(aA, bv, fa0, 0, 0, 0); \
      fa1 = __builtin_amdgcn_mfma_f32_32x32x16_bf16(aB, bv, fa1, 0, 0, 0); \
    }
    GENMM(ac0, ac4, bv0)
    GENMM(ac1, ac5, bv1)
    GENMM(ac2, ac6, bv2)
    GENMM(ac3, ac7, bv3)
#undef GENMM

    // ---- at jw boundary: reload A chunks for next jw (L2-hot) ----
    if ((s & 7) == 7) {
      int jn = (s >> 3) + 1;
      if (jn >= NJW) jn = 0;
      const short8* srcn = mv + jn * 2048;
      ac0 = srcn[mbase];
      ac1 = srcn[mbase + 64];
      ac2 = srcn[mbase + 128];
      ac3 = srcn[mbase + 192];
      ac4 = srcn[mbase + 256];
      ac5 = srcn[mbase + 320];
      ac6 = srcn[mbase + 384];
      ac7 = srcn[mbase + 448];
    }

    wv0 = nv0; wv1 = nv1;
  }

  // ---- C write: row = 64w + (r&3)+8*(r>>2)+4*(lane>>5) (+32 for fa1), col = n0+(lane&31) ----
  const int col   = n0 + (lane & 31);
  const int rbase = w * 64 + ((lane >> 5) << 2);
  if (atomic_mode) {
#pragma unroll
    for (int rr = 0; rr < 16; ++rr) {
      int row = rbase + (rr & 3) + ((rr >> 2) << 3);
      atomicAdd(&outp[(size_t)row * PROJ + col], fa0[rr]);
      atomicAdd(&outp[(size_t)(row + 32) * PROJ + col], fa1[rr]);
    }
  } else {
    float* dst = outp + (size_t)ps * BATCH * PROJ;
#pragma unroll
    for (int rr = 0; rr < 16; ++rr) {
      int row = rbase + (rr & 3) + ((rr >> 2) << 3);
      dst[(size_t)row * PROJ + col] = fa0[rr];
      dst[(size_t)(row + 32) * PROJ + col] = fa1[rr];
    }
  }
}

// ---------------- reduce + LN + MLP ----------------
__global__ __launch_bounds__(256)
void mlp_kernel(const float* __restrict__ part, int nps,
                const float* __restrict__ b1, const float* __restrict__ lng,
                const float* __restrict__ lnb, const float* __restrict__ W2,
                const float* __restrict__ b2, const float* __restrict__ g1,
                const float* __restrict__ bb1, const float* __restrict__ W3,
                const float* __restrict__ b3, const float* __restrict__ g2,
                const float* __restrict__ bb2, const float* __restrict__ W4,
                const float* __restrict__ b4, float* __restrict__ out) {
  __shared__ float h1[PROJ];
  __shared__ float h2[HID];
  __shared__ float h3[HID / 2];
  __shared__ float red[16];
  const int b = blockIdx.x, t = threadIdx.x;

  float f0 = 0.f, f1 = 0.f;
  const float* p0 = part + (size_t)b * PROJ + t;
#pragma unroll 4
  for (int s = 0; s < nps; ++s) {
    f0 += p0[0];
    f1 += p0[256];
    p0 += (size_t)BATCH * PROJ;
  }
  f0 += b1[t];
  f1 += b1[t + 256];

  float sum = f0 + f1, ss = f0 * f0 + f1 * f1;
#pragma unroll
  for (int o = 32; o > 0; o >>= 1) {
    sum += __shfl_xor(sum, o);
    ss  += __shfl_xor(ss, o);
  }
  const int wv = t >> 6, ln = t & 63;
  if (ln == 0) { red[wv] = sum; red[8 + wv] = ss; }
  __syncthreads();
  sum = red[0] + red[1] + red[2] + red[3];
  ss  = red[8] + red[9] + red[10] + red[11];
  float mu   = sum * (1.f / 512.f);
  float var  = ss * (1.f / 512.f) - mu * mu;
  float rstd = rsqrtf(var + 1e-5f);
  h1[t]       = fmaxf(0.f, (f0 - mu) * rstd * lng[t] + lnb[t]);
  h1[t + 256] = fmaxf(0.f, (f1 - mu) * rstd * lng[t + 256] + lnb[t + 256]);
  __syncthreads();

  const float bninv = rsqrtf(1.f + 1e-5f);
  {
    const f32x4* wr = (const f32x4*)(W2 + (size_t)t * PROJ);
    const f32x4* hv = (const f32x4*)h1;
    float a = 0.f;
#pragma unroll 4
    for (int i = 0; i < PROJ / 4; ++i) {
      f32x4 wq = wr[i], h = hv[i];
      a += wq[0] * h[0] + wq[1] * h[1] + wq[2] * h[2] + wq[3] * h[3];
    }
    h2[t] = fmaxf(0.f, (a + b2[t]) * bninv * g1[t] + bb1[t]);
  }
  __syncthreads();
  if (t < 128) {
    const f32x4* wr = (const f32x4*)(W3 + (size_t)t * HID);
    const f32x4* hv = (const f32x4*)h2;
    float a = 0.f;
#pragma unroll 4
    for (int i = 0; i < HID / 4; ++i) {
      f32x4 wq = wr[i], h = hv[i];
      a += wq[0] * h[0] + wq[1] * h[1] + wq[2] * h[2] + wq[3] * h[3];
    }
    h3[t] = fmaxf(0.f, (a + b3[t]) * bninv * g2[t] + bb2[t]);
  }
  __syncthreads();
  if (t < 2) {
    const float* wr = W4 + t * 128;
    float a = 0.f;
#pragma unroll 4
    for (int i = 0; i < 128; ++i) a += wr[i] * h3[i];
    out[b * 2 + t] = a + b4[t];
  }
}

extern "C" void kernel_launch(void* const* d_in, const int* in_sizes, int n_in,
                              void* d_out, int out_size, void* d_ws, size_t ws_size,
                              hipStream_t stream) {
  const float* x   = (const float*)d_in[0];
  const float* W1  = (const float*)d_in[1];
  const float* b1  = (const float*)d_in[2];
  const float* lng = (const float*)d_in[3];
  const float* lnb = (const float*)d_in[4];
  const float* W2  = (const float*)d_in[5];
  const float* b2  = (const float*)d_in[6];
  const float* g1  = (const float*)d_in[7];
  const float* bb1 = (const float*)d_in[8];
  const float* W3  = (const float*)d_in[9];
  const float* b3  = (const float*)d_in[10];
  const float* g2  = (const float*)d_in[11];
  const float* bb2 = (const float*)d_in[12];
  const float* W4  = (const float*)d_in[13];
  const float* b4  = (const float*)d_in[14];
  float* out = (float*)d_out;

  char* ws = (char*)d_ws;
  ushort_t* mF = (ushort_t*)ws;              // 384 KB (fragment-ordered bf16 m)
  float* big   = (float*)(ws + 524288);      // split-K partials

  size_t need = 524288 + (size_t)PSPLIT * BATCH * PROJ * 4;
  bool partial = ws_size >= need;

  hipLaunchKernelGGL(prep_kernel, dim3(256), dim3(256), 0, stream, x, mF);
  if (partial) {
    hipLaunchKernelGGL(einsum_kernel, dim3(NT * PSPLIT), dim3(256), 0, stream,
                       W1, mF, x, big, 0);
    hipLaunchKernelGGL(mlp_kernel, dim3(BATCH), dim3(256), 0, stream, big, PSPLIT,
                       b1, lng, lnb, W2, b2, g1, bb1, W3, b3, g2, bb2, W4, b4, out);
  } else {
    hipMemsetAsync(big, 0, (size_t)BATCH * PROJ * 4, stream);
    hipLaunchKernelGGL(einsum_kernel, dim3(NT * PSPLIT), dim3(256), 0, stream,
                       W1, mF, x, big, 1);
    hipLaunchKernelGGL(mlp_kernel, dim3(BATCH), dim3(256), 0, stream, big, 1,
                       b1, lng, lnb, W2, b2, g1, bb1, W3, b3, g2, bb2, W4, b4, out);
  }
}